// Round 16
// baseline (235.599 us; speedup 1.0000x reference)
//
#include <hip/hip_runtime.h>
#include <hip/hip_bf16.h>

typedef __attribute__((ext_vector_type(4))) float f32x4;
typedef __attribute__((ext_vector_type(8))) short bf16x8;

#define MFMA16(a, b, c) __builtin_amdgcn_mfma_f32_16x16x32_bf16((a), (b), (c), 0, 0, 0)

// ---- LDS layout (bytes): W1 64K + params ~2.6K = 68128 (R7+-proven).
#define W1T_OFF 0        // 128 n-rows x 256 k bf16, XOR-swizzled 8-chunks
#define B1_OFF  65536
#define G1_OFF  66048
#define E1_OFF  66560
#define B2_OFF  67072
#define G2_OFF  67328
#define E2_OFF  67584
#define W3_OFF  67840
#define B3_OFF  68096
#define SMEM_BYTES 68128

__device__ __forceinline__ short f2bf(float x) {
  __hip_bfloat16 h = __float2bfloat16(x);
  return __builtin_bit_cast(short, h);
}

__device__ __forceinline__ bf16x8 pack8(f32x4 a, f32x4 b) {
  bf16x8 r;
  r[0] = f2bf(a[0]); r[1] = f2bf(a[1]); r[2] = f2bf(a[2]); r[3] = f2bf(a[3]);
  r[4] = f2bf(b[0]); r[5] = f2bf(b[1]); r[6] = f2bf(b[2]); r[7] = f2bf(b[3]);
  return r;
}

// GELU via logistic CDF fit, log2e folded: z / (1 + exp2(z*(c1 + c2 z^2))).
// |err| <~ 5e-4. PROVEN: R4-R14 passed at absmax 0.0078. (R15's trans-free
// quartic FAILED accuracy: 0.0332 > 0.0277 threshold -- fit error amplifies
// through the layer-2 contraction. Do not retry without a rigorous bound.)
__device__ __forceinline__ float gelu_fast(float z) {
  float s = z * z;
  float y = z * __builtin_fmaf(-0.10180479f, s, -2.3048496f);
  float t = __builtin_amdgcn_exp2f(y);
  return z * __builtin_amdgcn_rcpf(1.0f + t);
}

// One-time weight prep into workspace (verified R9-R14):
//   w1i: W1 XOR-swizzled bf16 LDS image.
//   w2L: W2 pi-permuted fragments, lane-linear [(kb2*4+t)*512 + lane*8 + e].
//   forward pi: n -> k = (n>>5)*32 + ((n>>2)&3)*8 + ((n>>4)&1)*4 + (n&3)
__global__ __launch_bounds__(256) void prep_weights(
    const float* __restrict__ W1, const float* __restrict__ W2,
    short* __restrict__ w1i, short* __restrict__ w2L) {
  int idx = blockIdx.x * 256 + threadIdx.x;
  if (idx < 32768) {                       // W1 [k=256][n=128] row-major
    int k = idx >> 7, n = idx & 127;
    w1i[n * 256 + ((((k >> 3) ^ (n & 7)) << 3) | (k & 7))] = f2bf(W1[idx]);
  } else if (idx < 40960) {                // W2 [n=128][n2=64] row-major
    int j = idx - 32768;
    int n = j >> 6, n2 = j & 63;
    int kb2 = n >> 5;
    int qf = (n >> 2) & 3;
    int e = ((n >> 4) & 1) * 4 + (n & 3);
    int t = n2 >> 4, cc2 = n2 & 15;
    w2L[(kb2 * 4 + t) * 512 + (qf * 16 + cc2) * 8 + e] = f2bf(W2[j]);
  }
}

// One-time feature-table conversion f32 -> bf16 (R8-proven).
__global__ __launch_bounds__(256) void prep_feats(
    const float* __restrict__ f, short* __restrict__ o, int n8) {
  int idx = blockIdx.x * 256 + threadIdx.x;
  if (idx < n8) {
    f32x4 a = *(const f32x4*)(f + idx * 8);
    f32x4 b = *(const f32x4*)(f + idx * 8 + 4);
    *(bf16x8*)(o + idx * 8) = pack8(a, b);
  }
}

// Fused gather + (256->128 LN GELU) + (128->64 LN GELU) + (64->1).
// 8 waves/block (512 thr), mt=2 (32 edges/wave), 256-edge tiles, (512,1).
// = R14's proven 168.5us body (exp2 GELU, 4-deep gather ring, cross-tile idx
// prefetch, LN affine fold) + R15's exact vector-shaped LN stats (safe).
// pi-trick: layer-2 B operand = layer-1 accumulators (no H1 round-trip).
__global__ __launch_bounds__(512, 1) void mlp_fused(
    const short* __restrict__ drugb, const short* __restrict__ disb,
    const int* __restrict__ src, const int* __restrict__ dst,
    const short* __restrict__ w1i, const short* __restrict__ w2L,
    const float* __restrict__ b1, const float* __restrict__ g1, const float* __restrict__ be1,
    const float* __restrict__ b2, const float* __restrict__ g2, const float* __restrict__ be2,
    const float* __restrict__ W3, const float* __restrict__ b3,
    float* __restrict__ out, int E, int ntiles) {
  extern __shared__ char smem[];
  short* w1t = (short*)(smem + W1T_OFF);
  float* b1s = (float*)(smem + B1_OFF);
  float* g1s = (float*)(smem + G1_OFF);
  float* e1s = (float*)(smem + E1_OFF);
  float* b2s = (float*)(smem + B2_OFF);
  float* g2s = (float*)(smem + G2_OFF);
  float* e2s = (float*)(smem + E2_OFF);
  float* w3s = (float*)(smem + W3_OFF);
  float* b3s = (float*)(smem + B3_OFF);

  const int tid  = threadIdx.x;
  const int wave = tid >> 6;    // 0..7
  const int lane = tid & 63;
  const int q    = lane >> 4;   // quad (0..3)
  const int cc   = lane & 15;   // col-within-tile = edge slot

  // ---- one-time: linear copy of pre-swizzled 64KB W1 image into LDS ----
  #pragma unroll
  for (int o = 0; o < 8; ++o) {
    int s = (tid + o * 512) * 8;           // shorts; 16B/thread/pass, 8 passes
    *(bf16x8*)(w1t + s) = *(const bf16x8*)(w1i + s);
  }
  if (tid < 128) { b1s[tid] = b1[tid]; g1s[tid] = g1[tid]; e1s[tid] = be1[tid]; }
  else if (tid < 192) { int j = tid - 128; b2s[j] = b2[j]; g2s[j] = g2[j]; e2s[j] = be2[j]; w3s[j] = W3[j]; }
  if (tid == 256) b3s[0] = b3[0];
  __syncthreads();

  // per-lane W2 fragment base (lane-linear global, coalesced, L1-hot)
  const short* w2p = w2L + (lane << 3);

  // ---- cross-tile index prefetch: first tile's gather indices up front ----
  int s0i = 0, d0i = 0, s1i = 0, d1i = 0;
  {
    int r0 = blockIdx.x * 256 + wave * 32 + cc;
    int rc0 = (r0 < E) ? r0 : (E - 1);
    int rc1 = (r0 + 16 < E) ? (r0 + 16) : (E - 1);
    s0i = src[rc0]; d0i = dst[rc0]; s1i = src[rc1]; d1i = dst[rc1];
  }

  // ---- persistent loop over 256-edge tiles; waves free-run (no per-tile sync) ----
  for (int tile = blockIdx.x; tile < ntiles; tile += gridDim.x) {
    const int r0 = tile * 256 + wave * 32 + cc;       // mt=0 edge; mt=1 = r0+16
    const short* pd0 = drugb + (size_t)s0i * 128 + q * 8;
    const short* pq0 = disb  + (size_t)d0i * 128 + q * 8;
    const short* pd1 = drugb + (size_t)s1i * 128 + q * 8;
    const short* pq1 = disb  + (size_t)d1i * 128 + q * 8;

    // prologue: fill the 4-deep ring (kb 0..3, both edge streams) -> 8 loads in flight
    bf16x8 u[4][2];
    #pragma unroll
    for (int i = 0; i < 4; ++i) {
      u[i][0] = *(const bf16x8*)(pd0 + i * 32);
      u[i][1] = *(const bf16x8*)(pd1 + i * 32);
    }

    // prefetch NEXT tile's gather indices (hides idx->gather chain at tile start)
    {
      int tn = tile + gridDim.x;
      if (tn < ntiles) {
        int rn  = tn * 256 + wave * 32 + cc;
        int rcn0 = (rn < E) ? rn : (E - 1);
        int rcn1 = (rn + 16 < E) ? (rn + 16) : (E - 1);
        s0i = src[rcn0]; d0i = dst[rcn0]; s1i = src[rcn1]; d1i = dst[rcn1];
      }
    }

    // ===== layer 1: [256]->[128], K=256, acc init = b1 (bias folded) =====
    f32x4 acc1[8][2];
    #pragma unroll
    for (int nt = 0; nt < 8; ++nt) {
      f32x4 bv = *(const f32x4*)(b1s + nt * 16 + q * 4);
      acc1[nt][0] = bv;
      acc1[nt][1] = bv;
    }

    #pragma unroll
    for (int kb = 0; kb < 8; ++kb) {
      bf16x8 f0 = u[kb & 3][0];
      bf16x8 f1 = u[kb & 3][1];
      if (kb < 4) {                        // refill slot with kb+4 (= pq + kb*32)
        u[kb & 3][0] = *(const bf16x8*)(pq0 + kb * 32);
        u[kb & 3][1] = *(const bf16x8*)(pq1 + kb * 32);
      }
      const char* abase = (const char*)w1t + cc * 512 + ((((kb * 4 + q) ^ (cc & 7))) << 4);
      #pragma unroll
      for (int nt = 0; nt < 8; ++nt) {
        bf16x8 af = *(const bf16x8*)(abase + nt * 8192);   // one read, two MFMAs
        acc1[nt][0] = MFMA16(af, f0, acc1[nt][0]);
        acc1[nt][1] = MFMA16(af, f1, acc1[nt][1]);
      }
    }

    // epilogue 1: per-edge-group LN over n=128 (affine-folded), GELU, pack.
    // Stats accumulated as f32x4 vectors (exact; pack-friendly), horizontal at end.
    bf16x8 hreg[4][2];
    {
      f32x4 sv0 = acc1[0][0], sv1 = acc1[0][1];
      f32x4 qv0 = acc1[0][0] * acc1[0][0];
      f32x4 qv1 = acc1[0][1] * acc1[0][1];
      #pragma unroll
      for (int nt = 1; nt < 8; ++nt) {
        sv0 += acc1[nt][0];
        sv1 += acc1[nt][1];
        #pragma unroll
        for (int j = 0; j < 4; ++j) {
          qv0[j] = __builtin_fmaf(acc1[nt][0][j], acc1[nt][0][j], qv0[j]);
          qv1[j] = __builtin_fmaf(acc1[nt][1][j], acc1[nt][1][j], qv1[j]);
        }
      }
      float s0 = (sv0[0] + sv0[1]) + (sv0[2] + sv0[3]);
      float s1 = (sv1[0] + sv1[1]) + (sv1[2] + sv1[3]);
      float ss0 = (qv0[0] + qv0[1]) + (qv0[2] + qv0[3]);
      float ss1 = (qv1[0] + qv1[1]) + (qv1[2] + qv1[3]);
      s0  += __shfl_xor(s0, 16);  s0  += __shfl_xor(s0, 32);
      ss0 += __shfl_xor(ss0, 16); ss0 += __shfl_xor(ss0, 32);
      s1  += __shfl_xor(s1, 16);  s1  += __shfl_xor(s1, 32);
      ss1 += __shfl_xor(ss1, 16); ss1 += __shfl_xor(ss1, 32);
      float mu0 = s0 * 0.0078125f, mu1 = s1 * 0.0078125f;
      float va0 = ss0 * 0.0078125f - mu0 * mu0;
      float va1 = ss1 * 0.0078125f - mu1 * mu1;
      va0 = (va0 > 0.f) ? va0 : 0.f;
      va1 = (va1 > 0.f) ? va1 : 0.f;
      float rs0 = __builtin_amdgcn_rsqf(va0 + 1e-5f);
      float rs1 = __builtin_amdgcn_rsqf(va1 + 1e-5f);

      #pragma unroll
      for (int h = 0; h < 4; ++h) {
        f32x4 glo = *(const f32x4*)(g1s + (2 * h) * 16 + q * 4);
        f32x4 elo = *(const f32x4*)(e1s + (2 * h) * 16 + q * 4);
        f32x4 ghi = *(const f32x4*)(g1s + (2 * h + 1) * 16 + q * 4);
        f32x4 ehi = *(const f32x4*)(e1s + (2 * h + 1) * 16 + q * 4);
        // LN affine fold: z = x*(g*rs) + (be - mu*(g*rs)) -> 1 fma/value
        f32x4 al0, cl0, al1, cl1, ah0, ch0, ah1, ch1;
        #pragma unroll
        for (int j = 0; j < 4; ++j) {
          al0[j] = glo[j] * rs0; cl0[j] = __builtin_fmaf(-mu0, al0[j], elo[j]);
          al1[j] = glo[j] * rs1; cl1[j] = __builtin_fmaf(-mu1, al1[j], elo[j]);
          ah0[j] = ghi[j] * rs0; ch0[j] = __builtin_fmaf(-mu0, ah0[j], ehi[j]);
          ah1[j] = ghi[j] * rs1; ch1[j] = __builtin_fmaf(-mu1, ah1[j], ehi[j]);
        }
        f32x4 a0, b0, a1, b1v;
        #pragma unroll
        for (int j = 0; j < 4; ++j) {
          a0[j]  = gelu_fast(__builtin_fmaf(acc1[2 * h][0][j],     al0[j], cl0[j]));
          b0[j]  = gelu_fast(__builtin_fmaf(acc1[2 * h + 1][0][j], ah0[j], ch0[j]));
          a1[j]  = gelu_fast(__builtin_fmaf(acc1[2 * h][1][j],     al1[j], cl1[j]));
          b1v[j] = gelu_fast(__builtin_fmaf(acc1[2 * h + 1][1][j], ah1[j], ch1[j]));
        }
        hreg[h][0] = pack8(a0, b0);
        hreg[h][1] = pack8(a1, b1v);
      }
    }

    // ===== layer 2: [128]->[64], B operands = hreg (pi-permuted, lane-local),
    // A fragments lane-linear from global (L1-hot), fenced per kb2 =====
    f32x4 acc2[4][2];
    #pragma unroll
    for (int t = 0; t < 4; ++t) {
      f32x4 bv = *(const f32x4*)(b2s + t * 16 + q * 4);
      acc2[t][0] = bv;
      acc2[t][1] = bv;
    }

    #pragma unroll
    for (int kb2 = 0; kb2 < 4; ++kb2) {
      bf16x8 h0 = hreg[kb2][0];
      bf16x8 h1 = hreg[kb2][1];
      #pragma unroll
      for (int t = 0; t < 4; ++t) {
        bf16x8 af = *(const bf16x8*)(w2p + (kb2 * 4 + t) * 512);
        acc2[t][0] = MFMA16(af, h0, acc2[t][0]);
        acc2[t][1] = MFMA16(af, h1, acc2[t][1]);
      }
      __builtin_amdgcn_sched_barrier(0);   // keep W2 in-flight bounded (R13-proven)
    }

    // epilogue 2: LN over n=64 per edge-group, GELU, dot with W3, +b3, store
    {
      f32x4 sv0 = acc2[0][0], sv1 = acc2[0][1];
      f32x4 qv0 = acc2[0][0] * acc2[0][0];
      f32x4 qv1 = acc2[0][1] * acc2[0][1];
      #pragma unroll
      for (int t = 1; t < 4; ++t) {
        sv0 += acc2[t][0];
        sv1 += acc2[t][1];
        #pragma unroll
        for (int j = 0; j < 4; ++j) {
          qv0[j] = __builtin_fmaf(acc2[t][0][j], acc2[t][0][j], qv0[j]);
          qv1[j] = __builtin_fmaf(acc2[t][1][j], acc2[t][1][j], qv1[j]);
        }
      }
      float s0 = (sv0[0] + sv0[1]) + (sv0[2] + sv0[3]);
      float s1 = (sv1[0] + sv1[1]) + (sv1[2] + sv1[3]);
      float ss0 = (qv0[0] + qv0[1]) + (qv0[2] + qv0[3]);
      float ss1 = (qv1[0] + qv1[1]) + (qv1[2] + qv1[3]);
      s0  += __shfl_xor(s0, 16);  s0  += __shfl_xor(s0, 32);
      ss0 += __shfl_xor(ss0, 16); ss0 += __shfl_xor(ss0, 32);
      s1  += __shfl_xor(s1, 16);  s1  += __shfl_xor(s1, 32);
      ss1 += __shfl_xor(ss1, 16); ss1 += __shfl_xor(ss1, 32);
      float mu0 = s0 * 0.015625f, mu1 = s1 * 0.015625f;
      float va0 = ss0 * 0.015625f - mu0 * mu0;
      float va1 = ss1 * 0.015625f - mu1 * mu1;
      va0 = (va0 > 0.f) ? va0 : 0.f;
      va1 = (va1 > 0.f) ? va1 : 0.f;
      float rs0 = __builtin_amdgcn_rsqf(va0 + 1e-5f);
      float rs1 = __builtin_amdgcn_rsqf(va1 + 1e-5f);

      float dot0 = 0.f, dot1 = 0.f;
      #pragma unroll
      for (int t = 0; t < 4; ++t) {
        f32x4 gv = *(const f32x4*)(g2s + t * 16 + q * 4);
        f32x4 ev = *(const f32x4*)(e2s + t * 16 + q * 4);
        f32x4 wv = *(const f32x4*)(w3s + t * 16 + q * 4);
        #pragma unroll
        for (int j = 0; j < 4; ++j) {
          float z0 = __builtin_fmaf((acc2[t][0][j] - mu0) * rs0, gv[j], ev[j]);
          float z1 = __builtin_fmaf((acc2[t][1][j] - mu1) * rs1, gv[j], ev[j]);
          dot0 = __builtin_fmaf(gelu_fast(z0), wv[j], dot0);
          dot1 = __builtin_fmaf(gelu_fast(z1), wv[j], dot1);
        }
      }
      dot0 += __shfl_xor(dot0, 16); dot0 += __shfl_xor(dot0, 32);
      dot1 += __shfl_xor(dot1, 16); dot1 += __shfl_xor(dot1, 32);
      if (q == 0) {
        float bias3 = b3s[0];
        if (r0 < E)      out[r0]      = dot0 + bias3;
        if (r0 + 16 < E) out[r0 + 16] = dot1 + bias3;
      }
    }
  }
}

extern "C" void kernel_launch(void* const* d_in, const int* in_sizes, int n_in,
                              void* d_out, int out_size, void* d_ws, size_t ws_size,
                              hipStream_t stream) {
  const float* drug = (const float*)d_in[0];
  const float* dis  = (const float*)d_in[1];
  const int*   src  = (const int*)d_in[2];
  const int*   dst  = (const int*)d_in[3];
  const float* W1   = (const float*)d_in[4];
  const float* b1   = (const float*)d_in[5];
  const float* g1   = (const float*)d_in[6];
  const float* be1  = (const float*)d_in[7];
  const float* W2   = (const float*)d_in[8];
  const float* b2   = (const float*)d_in[9];
  const float* g2   = (const float*)d_in[10];
  const float* be2  = (const float*)d_in[11];
  const float* W3   = (const float*)d_in[12];
  const float* b3   = (const float*)d_in[13];
  float* out = (float*)d_out;

  const int E      = in_sizes[2];
  const int ndrug8 = in_sizes[0] / 8;
  const int ndis8  = in_sizes[1] / 8;
  const int ntiles = (E + 255) / 256;      // 256-edge tiles (8 waves x 32 edges)

  short* w1i   = (short*)d_ws;             // 32768 shorts (full LDS image)
  short* w2L   = w1i + 32768;              // 8192 shorts (W2 lane-linear)
  short* drugb = w2L + 8192;               // bf16 feature tables
  short* disb  = drugb + (size_t)ndrug8 * 8;

  (void)hipFuncSetAttribute((const void*)mlp_fused,
                            hipFuncAttributeMaxDynamicSharedMemorySize, SMEM_BYTES);

  prep_weights<<<dim3(160), dim3(256), 0, stream>>>(W1, W2, w1i, w2L);
  prep_feats<<<dim3((ndrug8 + 255) / 256), dim3(256), 0, stream>>>(drug, drugb, ndrug8);
  prep_feats<<<dim3((ndis8 + 255) / 256), dim3(256), 0, stream>>>(dis, disb, ndis8);

  int grid = 512;
  if (ntiles < grid) grid = ntiles;
  mlp_fused<<<dim3(grid), dim3(512), SMEM_BYTES, stream>>>(
      drugb, disb, src, dst, w1i, w2L,
      b1, g1, be1, b2, g2, be2, W3, b3, out, E, ntiles);
}

// Round 17
// 225.353 us; speedup vs baseline: 1.0455x; 1.0455x over previous
//
#include <hip/hip_runtime.h>
#include <hip/hip_bf16.h>

typedef __attribute__((ext_vector_type(4))) float f32x4;
typedef __attribute__((ext_vector_type(8))) short bf16x8;

#define MFMA16(a, b, c) __builtin_amdgcn_mfma_f32_16x16x32_bf16((a), (b), (c), 0, 0, 0)

// ---- LDS layout (bytes): W1 64K + params ~2.6K = 68128 (R7+-proven).
#define W1T_OFF 0        // 128 n-rows x 256 k bf16, XOR-swizzled 8-chunks
#define B1_OFF  65536
#define G1_OFF  66048
#define E1_OFF  66560
#define B2_OFF  67072
#define G2_OFF  67328
#define E2_OFF  67584
#define W3_OFF  67840
#define B3_OFF  68096
#define SMEM_BYTES 68128

__device__ __forceinline__ short f2bf(float x) {
  __hip_bfloat16 h = __float2bfloat16(x);
  return __builtin_bit_cast(short, h);
}

__device__ __forceinline__ bf16x8 pack8(f32x4 a, f32x4 b) {
  bf16x8 r;
  r[0] = f2bf(a[0]); r[1] = f2bf(a[1]); r[2] = f2bf(a[2]); r[3] = f2bf(a[3]);
  r[4] = f2bf(b[0]); r[5] = f2bf(b[1]); r[6] = f2bf(b[2]); r[7] = f2bf(b[3]);
  return r;
}

// GELU via logistic CDF fit, log2e folded: z / (1 + exp2(z*(c1 + c2 z^2))).
// |err| <~ 5e-4. PROVEN: R4-R16 passed at absmax 0.0078. (R15's trans-free
// quartic FAILED accuracy 0.0332 -- do not retry without a rigorous bound.)
__device__ __forceinline__ float gelu_fast(float z) {
  float s = z * z;
  float y = z * __builtin_fmaf(-0.10180479f, s, -2.3048496f);
  float t = __builtin_amdgcn_exp2f(y);
  return z * __builtin_amdgcn_rcpf(1.0f + t);
}

// One-time weight prep into workspace (verified R9-R16):
//   w1i: W1 XOR-swizzled bf16 LDS image.
//   w2L: W2 pi-permuted fragments, lane-linear [(kb2*4+t)*512 + lane*8 + e].
//   forward pi: n -> k = (n>>5)*32 + ((n>>2)&3)*8 + ((n>>4)&1)*4 + (n&3)
__global__ __launch_bounds__(256) void prep_weights(
    const float* __restrict__ W1, const float* __restrict__ W2,
    short* __restrict__ w1i, short* __restrict__ w2L) {
  int idx = blockIdx.x * 256 + threadIdx.x;
  if (idx < 32768) {                       // W1 [k=256][n=128] row-major
    int k = idx >> 7, n = idx & 127;
    w1i[n * 256 + ((((k >> 3) ^ (n & 7)) << 3) | (k & 7))] = f2bf(W1[idx]);
  } else if (idx < 40960) {                // W2 [n=128][n2=64] row-major
    int j = idx - 32768;
    int n = j >> 6, n2 = j & 63;
    int kb2 = n >> 5;
    int qf = (n >> 2) & 3;
    int e = ((n >> 4) & 1) * 4 + (n & 3);
    int t = n2 >> 4, cc2 = n2 & 15;
    w2L[(kb2 * 4 + t) * 512 + (qf * 16 + cc2) * 8 + e] = f2bf(W2[j]);
  }
}

// One-time feature-table conversion f32 -> bf16 (R8-proven).
__global__ __launch_bounds__(256) void prep_feats(
    const float* __restrict__ f, short* __restrict__ o, int n8) {
  int idx = blockIdx.x * 256 + threadIdx.x;
  if (idx < n8) {
    f32x4 a = *(const f32x4*)(f + idx * 8);
    f32x4 b = *(const f32x4*)(f + idx * 8 + 4);
    *(bf16x8*)(o + idx * 8) = pack8(a, b);
  }
}

// Fused gather + (256->128 LN GELU) + (128->64 LN GELU) + (64->1).
// 8 waves/block (512 thr), mt=2 (32 edges/wave), 256-edge tiles, (512,1).
// R17 changes vs R16 (161.5us steady):
//  - W2 fragments explicitly preloaded into wf[16] (64 regs) right after the
//    layer-1 MFMA loop: their L1 latency hides under epilogue-1's ~2000cy of
//    VALU. The layer-2 sched_barrier fence (needed under the old 64-reg
//    budget, R7-R13) is DELETED -- under (512,1) it only blocked this overlap.
//  - s_setprio(1) around MFMA clusters (waves free-run at drifted phases ->
//    arbitration favors the matrix pipe; attn-regime evidence +4-7%).
// pi-trick: layer-2 B operand = layer-1 accumulators (no H1 round-trip).
__global__ __launch_bounds__(512, 1) void mlp_fused(
    const short* __restrict__ drugb, const short* __restrict__ disb,
    const int* __restrict__ src, const int* __restrict__ dst,
    const short* __restrict__ w1i, const short* __restrict__ w2L,
    const float* __restrict__ b1, const float* __restrict__ g1, const float* __restrict__ be1,
    const float* __restrict__ b2, const float* __restrict__ g2, const float* __restrict__ be2,
    const float* __restrict__ W3, const float* __restrict__ b3,
    float* __restrict__ out, int E, int ntiles) {
  extern __shared__ char smem[];
  short* w1t = (short*)(smem + W1T_OFF);
  float* b1s = (float*)(smem + B1_OFF);
  float* g1s = (float*)(smem + G1_OFF);
  float* e1s = (float*)(smem + E1_OFF);
  float* b2s = (float*)(smem + B2_OFF);
  float* g2s = (float*)(smem + G2_OFF);
  float* e2s = (float*)(smem + E2_OFF);
  float* w3s = (float*)(smem + W3_OFF);
  float* b3s = (float*)(smem + B3_OFF);

  const int tid  = threadIdx.x;
  const int wave = tid >> 6;    // 0..7
  const int lane = tid & 63;
  const int q    = lane >> 4;   // quad (0..3)
  const int cc   = lane & 15;   // col-within-tile = edge slot

  // ---- one-time: linear copy of pre-swizzled 64KB W1 image into LDS ----
  #pragma unroll
  for (int o = 0; o < 8; ++o) {
    int s = (tid + o * 512) * 8;           // shorts; 16B/thread/pass, 8 passes
    *(bf16x8*)(w1t + s) = *(const bf16x8*)(w1i + s);
  }
  if (tid < 128) { b1s[tid] = b1[tid]; g1s[tid] = g1[tid]; e1s[tid] = be1[tid]; }
  else if (tid < 192) { int j = tid - 128; b2s[j] = b2[j]; g2s[j] = g2[j]; e2s[j] = be2[j]; w3s[j] = W3[j]; }
  if (tid == 256) b3s[0] = b3[0];
  __syncthreads();

  // per-lane W2 fragment base (lane-linear global, coalesced, L1-hot)
  const short* w2p = w2L + (lane << 3);

  // ---- cross-tile index prefetch: first tile's gather indices up front ----
  int s0i = 0, d0i = 0, s1i = 0, d1i = 0;
  {
    int r0 = blockIdx.x * 256 + wave * 32 + cc;
    int rc0 = (r0 < E) ? r0 : (E - 1);
    int rc1 = (r0 + 16 < E) ? (r0 + 16) : (E - 1);
    s0i = src[rc0]; d0i = dst[rc0]; s1i = src[rc1]; d1i = dst[rc1];
  }

  // ---- persistent loop over 256-edge tiles; waves free-run (no per-tile sync) ----
  for (int tile = blockIdx.x; tile < ntiles; tile += gridDim.x) {
    const int r0 = tile * 256 + wave * 32 + cc;       // mt=0 edge; mt=1 = r0+16
    const short* pd0 = drugb + (size_t)s0i * 128 + q * 8;
    const short* pq0 = disb  + (size_t)d0i * 128 + q * 8;
    const short* pd1 = drugb + (size_t)s1i * 128 + q * 8;
    const short* pq1 = disb  + (size_t)d1i * 128 + q * 8;

    // prologue: fill the 4-deep ring (kb 0..3, both edge streams) -> 8 loads in flight
    bf16x8 u[4][2];
    #pragma unroll
    for (int i = 0; i < 4; ++i) {
      u[i][0] = *(const bf16x8*)(pd0 + i * 32);
      u[i][1] = *(const bf16x8*)(pd1 + i * 32);
    }

    // prefetch NEXT tile's gather indices (hides idx->gather chain at tile start)
    {
      int tn = tile + gridDim.x;
      if (tn < ntiles) {
        int rn  = tn * 256 + wave * 32 + cc;
        int rcn0 = (rn < E) ? rn : (E - 1);
        int rcn1 = (rn + 16 < E) ? (rn + 16) : (E - 1);
        s0i = src[rcn0]; d0i = dst[rcn0]; s1i = src[rcn1]; d1i = dst[rcn1];
      }
    }

    // ===== layer 1: [256]->[128], K=256, acc init = b1 (bias folded) =====
    f32x4 acc1[8][2];
    #pragma unroll
    for (int nt = 0; nt < 8; ++nt) {
      f32x4 bv = *(const f32x4*)(b1s + nt * 16 + q * 4);
      acc1[nt][0] = bv;
      acc1[nt][1] = bv;
    }

    __builtin_amdgcn_s_setprio(1);
    #pragma unroll
    for (int kb = 0; kb < 8; ++kb) {
      bf16x8 f0 = u[kb & 3][0];
      bf16x8 f1 = u[kb & 3][1];
      if (kb < 4) {                        // refill slot with kb+4 (= pq + kb*32)
        u[kb & 3][0] = *(const bf16x8*)(pq0 + kb * 32);
        u[kb & 3][1] = *(const bf16x8*)(pq1 + kb * 32);
      }
      const char* abase = (const char*)w1t + cc * 512 + ((((kb * 4 + q) ^ (cc & 7))) << 4);
      #pragma unroll
      for (int nt = 0; nt < 8; ++nt) {
        bf16x8 af = *(const bf16x8*)(abase + nt * 8192);   // one read, two MFMAs
        acc1[nt][0] = MFMA16(af, f0, acc1[nt][0]);
        acc1[nt][1] = MFMA16(af, f1, acc1[nt][1]);
      }
    }
    __builtin_amdgcn_s_setprio(0);

    // W2 preload: issue all 16 fragment loads NOW (L1-hot, 64 regs in flight);
    // latency hides under epilogue-1's VALU work. (512,1) budget makes this free.
    bf16x8 wf[16];
    #pragma unroll
    for (int i = 0; i < 16; ++i)
      wf[i] = *(const bf16x8*)(w2p + i * 512);

    // epilogue 1: per-edge-group LN over n=128 (affine-folded), GELU, pack.
    // Stats accumulated as f32x4 vectors (exact; pack-friendly), horizontal at end.
    bf16x8 hreg[4][2];
    {
      f32x4 sv0 = acc1[0][0], sv1 = acc1[0][1];
      f32x4 qv0 = acc1[0][0] * acc1[0][0];
      f32x4 qv1 = acc1[0][1] * acc1[0][1];
      #pragma unroll
      for (int nt = 1; nt < 8; ++nt) {
        sv0 += acc1[nt][0];
        sv1 += acc1[nt][1];
        #pragma unroll
        for (int j = 0; j < 4; ++j) {
          qv0[j] = __builtin_fmaf(acc1[nt][0][j], acc1[nt][0][j], qv0[j]);
          qv1[j] = __builtin_fmaf(acc1[nt][1][j], acc1[nt][1][j], qv1[j]);
        }
      }
      float s0 = (sv0[0] + sv0[1]) + (sv0[2] + sv0[3]);
      float s1 = (sv1[0] + sv1[1]) + (sv1[2] + sv1[3]);
      float ss0 = (qv0[0] + qv0[1]) + (qv0[2] + qv0[3]);
      float ss1 = (qv1[0] + qv1[1]) + (qv1[2] + qv1[3]);
      s0  += __shfl_xor(s0, 16);  s0  += __shfl_xor(s0, 32);
      ss0 += __shfl_xor(ss0, 16); ss0 += __shfl_xor(ss0, 32);
      s1  += __shfl_xor(s1, 16);  s1  += __shfl_xor(s1, 32);
      ss1 += __shfl_xor(ss1, 16); ss1 += __shfl_xor(ss1, 32);
      float mu0 = s0 * 0.0078125f, mu1 = s1 * 0.0078125f;
      float va0 = ss0 * 0.0078125f - mu0 * mu0;
      float va1 = ss1 * 0.0078125f - mu1 * mu1;
      va0 = (va0 > 0.f) ? va0 : 0.f;
      va1 = (va1 > 0.f) ? va1 : 0.f;
      float rs0 = __builtin_amdgcn_rsqf(va0 + 1e-5f);
      float rs1 = __builtin_amdgcn_rsqf(va1 + 1e-5f);

      #pragma unroll
      for (int h = 0; h < 4; ++h) {
        f32x4 glo = *(const f32x4*)(g1s + (2 * h) * 16 + q * 4);
        f32x4 elo = *(const f32x4*)(e1s + (2 * h) * 16 + q * 4);
        f32x4 ghi = *(const f32x4*)(g1s + (2 * h + 1) * 16 + q * 4);
        f32x4 ehi = *(const f32x4*)(e1s + (2 * h + 1) * 16 + q * 4);
        // LN affine fold: z = x*(g*rs) + (be - mu*(g*rs)) -> 1 fma/value
        f32x4 al0, cl0, al1, cl1, ah0, ch0, ah1, ch1;
        #pragma unroll
        for (int j = 0; j < 4; ++j) {
          al0[j] = glo[j] * rs0; cl0[j] = __builtin_fmaf(-mu0, al0[j], elo[j]);
          al1[j] = glo[j] * rs1; cl1[j] = __builtin_fmaf(-mu1, al1[j], elo[j]);
          ah0[j] = ghi[j] * rs0; ch0[j] = __builtin_fmaf(-mu0, ah0[j], ehi[j]);
          ah1[j] = ghi[j] * rs1; ch1[j] = __builtin_fmaf(-mu1, ah1[j], ehi[j]);
        }
        f32x4 a0, b0, a1, b1v;
        #pragma unroll
        for (int j = 0; j < 4; ++j) {
          a0[j]  = gelu_fast(__builtin_fmaf(acc1[2 * h][0][j],     al0[j], cl0[j]));
          b0[j]  = gelu_fast(__builtin_fmaf(acc1[2 * h + 1][0][j], ah0[j], ch0[j]));
          a1[j]  = gelu_fast(__builtin_fmaf(acc1[2 * h][1][j],     al1[j], cl1[j]));
          b1v[j] = gelu_fast(__builtin_fmaf(acc1[2 * h + 1][1][j], ah1[j], ch1[j]));
        }
        hreg[h][0] = pack8(a0, b0);
        hreg[h][1] = pack8(a1, b1v);
      }
    }

    // ===== layer 2: [128]->[64], register-resident A (wf) and B (hreg) =====
    f32x4 acc2[4][2];
    #pragma unroll
    for (int t = 0; t < 4; ++t) {
      f32x4 bv = *(const f32x4*)(b2s + t * 16 + q * 4);
      acc2[t][0] = bv;
      acc2[t][1] = bv;
    }

    __builtin_amdgcn_s_setprio(1);
    #pragma unroll
    for (int kb2 = 0; kb2 < 4; ++kb2) {
      bf16x8 h0 = hreg[kb2][0];
      bf16x8 h1 = hreg[kb2][1];
      #pragma unroll
      for (int t = 0; t < 4; ++t) {
        bf16x8 af = wf[kb2 * 4 + t];
        acc2[t][0] = MFMA16(af, h0, acc2[t][0]);
        acc2[t][1] = MFMA16(af, h1, acc2[t][1]);
      }
    }
    __builtin_amdgcn_s_setprio(0);

    // epilogue 2: LN over n=64 per edge-group, GELU, dot with W3, +b3, store
    {
      f32x4 sv0 = acc2[0][0], sv1 = acc2[0][1];
      f32x4 qv0 = acc2[0][0] * acc2[0][0];
      f32x4 qv1 = acc2[0][1] * acc2[0][1];
      #pragma unroll
      for (int t = 1; t < 4; ++t) {
        sv0 += acc2[t][0];
        sv1 += acc2[t][1];
        #pragma unroll
        for (int j = 0; j < 4; ++j) {
          qv0[j] = __builtin_fmaf(acc2[t][0][j], acc2[t][0][j], qv0[j]);
          qv1[j] = __builtin_fmaf(acc2[t][1][j], acc2[t][1][j], qv1[j]);
        }
      }
      float s0 = (sv0[0] + sv0[1]) + (sv0[2] + sv0[3]);
      float s1 = (sv1[0] + sv1[1]) + (sv1[2] + sv1[3]);
      float ss0 = (qv0[0] + qv0[1]) + (qv0[2] + qv0[3]);
      float ss1 = (qv1[0] + qv1[1]) + (qv1[2] + qv1[3]);
      s0  += __shfl_xor(s0, 16);  s0  += __shfl_xor(s0, 32);
      ss0 += __shfl_xor(ss0, 16); ss0 += __shfl_xor(ss0, 32);
      s1  += __shfl_xor(s1, 16);  s1  += __shfl_xor(s1, 32);
      ss1 += __shfl_xor(ss1, 16); ss1 += __shfl_xor(ss1, 32);
      float mu0 = s0 * 0.015625f, mu1 = s1 * 0.015625f;
      float va0 = ss0 * 0.015625f - mu0 * mu0;
      float va1 = ss1 * 0.015625f - mu1 * mu1;
      va0 = (va0 > 0.f) ? va0 : 0.f;
      va1 = (va1 > 0.f) ? va1 : 0.f;
      float rs0 = __builtin_amdgcn_rsqf(va0 + 1e-5f);
      float rs1 = __builtin_amdgcn_rsqf(va1 + 1e-5f);

      float dot0 = 0.f, dot1 = 0.f;
      #pragma unroll
      for (int t = 0; t < 4; ++t) {
        f32x4 gv = *(const f32x4*)(g2s + t * 16 + q * 4);
        f32x4 ev = *(const f32x4*)(e2s + t * 16 + q * 4);
        f32x4 wv = *(const f32x4*)(w3s + t * 16 + q * 4);
        #pragma unroll
        for (int j = 0; j < 4; ++j) {
          float z0 = __builtin_fmaf((acc2[t][0][j] - mu0) * rs0, gv[j], ev[j]);
          float z1 = __builtin_fmaf((acc2[t][1][j] - mu1) * rs1, gv[j], ev[j]);
          dot0 = __builtin_fmaf(gelu_fast(z0), wv[j], dot0);
          dot1 = __builtin_fmaf(gelu_fast(z1), wv[j], dot1);
        }
      }
      dot0 += __shfl_xor(dot0, 16); dot0 += __shfl_xor(dot0, 32);
      dot1 += __shfl_xor(dot1, 16); dot1 += __shfl_xor(dot1, 32);
      if (q == 0) {
        float bias3 = b3s[0];
        if (r0 < E)      out[r0]      = dot0 + bias3;
        if (r0 + 16 < E) out[r0 + 16] = dot1 + bias3;
      }
    }
  }
}

extern "C" void kernel_launch(void* const* d_in, const int* in_sizes, int n_in,
                              void* d_out, int out_size, void* d_ws, size_t ws_size,
                              hipStream_t stream) {
  const float* drug = (const float*)d_in[0];
  const float* dis  = (const float*)d_in[1];
  const int*   src  = (const int*)d_in[2];
  const int*   dst  = (const int*)d_in[3];
  const float* W1   = (const float*)d_in[4];
  const float* b1   = (const float*)d_in[5];
  const float* g1   = (const float*)d_in[6];
  const float* be1  = (const float*)d_in[7];
  const float* W2   = (const float*)d_in[8];
  const float* b2   = (const float*)d_in[9];
  const float* g2   = (const float*)d_in[10];
  const float* be2  = (const float*)d_in[11];
  const float* W3   = (const float*)d_in[12];
  const float* b3   = (const float*)d_in[13];
  float* out = (float*)d_out;

  const int E      = in_sizes[2];
  const int ndrug8 = in_sizes[0] / 8;
  const int ndis8  = in_sizes[1] / 8;
  const int ntiles = (E + 255) / 256;      // 256-edge tiles (8 waves x 32 edges)

  short* w1i   = (short*)d_ws;             // 32768 shorts (full LDS image)
  short* w2L   = w1i + 32768;              // 8192 shorts (W2 lane-linear)
  short* drugb = w2L + 8192;               // bf16 feature tables
  short* disb  = drugb + (size_t)ndrug8 * 8;

  (void)hipFuncSetAttribute((const void*)mlp_fused,
                            hipFuncAttributeMaxDynamicSharedMemorySize, SMEM_BYTES);

  prep_weights<<<dim3(160), dim3(256), 0, stream>>>(W1, W2, w1i, w2L);
  prep_feats<<<dim3((ndrug8 + 255) / 256), dim3(256), 0, stream>>>(drug, drugb, ndrug8);
  prep_feats<<<dim3((ndis8 + 255) / 256), dim3(256), 0, stream>>>(dis, disb, ndis8);

  int grid = 512;
  if (ntiles < grid) grid = ntiles;
  mlp_fused<<<dim3(grid), dim3(512), SMEM_BYTES, stream>>>(
      drugb, disb, src, dst, w1i, w2L,
      b1, g1, be1, b2, g2, be2, W3, b3, out, E, ntiles);
}

// Round 18
// 218.875 us; speedup vs baseline: 1.0764x; 1.0296x over previous
//
#include <hip/hip_runtime.h>
#include <hip/hip_bf16.h>

typedef __attribute__((ext_vector_type(4))) float f32x4;
typedef __attribute__((ext_vector_type(8))) short bf16x8;

#define MFMA16(a, b, c) __builtin_amdgcn_mfma_f32_16x16x32_bf16((a), (b), (c), 0, 0, 0)

// ---- LDS layout (bytes): W1 64K + params ~2.6K = 68128 (R7+-proven).
#define W1T_OFF 0        // 128 n-rows x 256 k bf16, XOR-swizzled 8-chunks
#define B1_OFF  65536
#define G1_OFF  66048
#define E1_OFF  66560
#define B2_OFF  67072
#define G2_OFF  67328
#define E2_OFF  67584
#define W3_OFF  67840
#define B3_OFF  68096
#define SMEM_BYTES 68128

__device__ __forceinline__ short f2bf(float x) {
  __hip_bfloat16 h = __float2bfloat16(x);
  return __builtin_bit_cast(short, h);
}

__device__ __forceinline__ bf16x8 pack8(f32x4 a, f32x4 b) {
  bf16x8 r;
  r[0] = f2bf(a[0]); r[1] = f2bf(a[1]); r[2] = f2bf(a[2]); r[3] = f2bf(a[3]);
  r[4] = f2bf(b[0]); r[5] = f2bf(b[1]); r[6] = f2bf(b[2]); r[7] = f2bf(b[3]);
  return r;
}

// GELU via logistic CDF fit, log2e folded: z / (1 + exp2(z*(c1 + c2 z^2))).
// |err| <~ 5e-4. PROVEN: R4-R17 passed at absmax 0.0078. (R15's trans-free
// quartic FAILED accuracy 0.0332 -- do not retry without a rigorous bound.)
// R18: vector form -- poly pre/post as f32x4 expressions (backend can select
// v_pk_fma_f32 dual-issue); exp2/rcp have no packed form, stay scalar.
__device__ __forceinline__ f32x4 gelu4(f32x4 z) {
  f32x4 s = z * z;
  f32x4 y = z * (s * -0.10180479f + -2.3048496f);
  f32x4 t;
  t[0] = __builtin_amdgcn_exp2f(y[0]);
  t[1] = __builtin_amdgcn_exp2f(y[1]);
  t[2] = __builtin_amdgcn_exp2f(y[2]);
  t[3] = __builtin_amdgcn_exp2f(y[3]);
  f32x4 d = t + 1.0f;
  f32x4 r;
  r[0] = __builtin_amdgcn_rcpf(d[0]);
  r[1] = __builtin_amdgcn_rcpf(d[1]);
  r[2] = __builtin_amdgcn_rcpf(d[2]);
  r[3] = __builtin_amdgcn_rcpf(d[3]);
  return z * r;
}

// One-time weight prep into workspace (verified R9-R17):
//   w1i: W1 XOR-swizzled bf16 LDS image.
//   w2L: W2 pi-permuted fragments, lane-linear [(kb2*4+t)*512 + lane*8 + e].
//   forward pi: n -> k = (n>>5)*32 + ((n>>2)&3)*8 + ((n>>4)&1)*4 + (n&3)
__global__ __launch_bounds__(256) void prep_weights(
    const float* __restrict__ W1, const float* __restrict__ W2,
    short* __restrict__ w1i, short* __restrict__ w2L) {
  int idx = blockIdx.x * 256 + threadIdx.x;
  if (idx < 32768) {                       // W1 [k=256][n=128] row-major
    int k = idx >> 7, n = idx & 127;
    w1i[n * 256 + ((((k >> 3) ^ (n & 7)) << 3) | (k & 7))] = f2bf(W1[idx]);
  } else if (idx < 40960) {                // W2 [n=128][n2=64] row-major
    int j = idx - 32768;
    int n = j >> 6, n2 = j & 63;
    int kb2 = n >> 5;
    int qf = (n >> 2) & 3;
    int e = ((n >> 4) & 1) * 4 + (n & 3);
    int t = n2 >> 4, cc2 = n2 & 15;
    w2L[(kb2 * 4 + t) * 512 + (qf * 16 + cc2) * 8 + e] = f2bf(W2[j]);
  }
}

// One-time feature-table conversion f32 -> bf16 (R8-proven).
__global__ __launch_bounds__(256) void prep_feats(
    const float* __restrict__ f, short* __restrict__ o, int n8) {
  int idx = blockIdx.x * 256 + threadIdx.x;
  if (idx < n8) {
    f32x4 a = *(const f32x4*)(f + idx * 8);
    f32x4 b = *(const f32x4*)(f + idx * 8 + 4);
    *(bf16x8*)(o + idx * 8) = pack8(a, b);
  }
}

// Fused gather + (256->128 LN GELU) + (128->64 LN GELU) + (64->1).
// 8 waves/block (512 thr), mt=2 (32 edges/wave), 256-edge tiles, (512,1).
// R18 vs R17 (155.9us): whole-f32x4 vector expressions throughout both
// epilogues (LN affine, GELU pre/post, W3 dot) -> backend can dual-issue
// via v_pk_fma_f32; affine fold extended to epilogue 2. VALU issue is the
// binding resource (51% busy; MFMA 23%; occupancy runtime-capped 8 waves/CU;
// VGPR hard-capped 128 at 512-thr (R16: spill at exactly 128 under (512,1))).
// pi-trick: layer-2 B operand = layer-1 accumulators (no H1 round-trip).
__global__ __launch_bounds__(512, 1) void mlp_fused(
    const short* __restrict__ drugb, const short* __restrict__ disb,
    const int* __restrict__ src, const int* __restrict__ dst,
    const short* __restrict__ w1i, const short* __restrict__ w2L,
    const float* __restrict__ b1, const float* __restrict__ g1, const float* __restrict__ be1,
    const float* __restrict__ b2, const float* __restrict__ g2, const float* __restrict__ be2,
    const float* __restrict__ W3, const float* __restrict__ b3,
    float* __restrict__ out, int E, int ntiles) {
  extern __shared__ char smem[];
  short* w1t = (short*)(smem + W1T_OFF);
  float* b1s = (float*)(smem + B1_OFF);
  float* g1s = (float*)(smem + G1_OFF);
  float* e1s = (float*)(smem + E1_OFF);
  float* b2s = (float*)(smem + B2_OFF);
  float* g2s = (float*)(smem + G2_OFF);
  float* e2s = (float*)(smem + E2_OFF);
  float* w3s = (float*)(smem + W3_OFF);
  float* b3s = (float*)(smem + B3_OFF);

  const int tid  = threadIdx.x;
  const int wave = tid >> 6;    // 0..7
  const int lane = tid & 63;
  const int q    = lane >> 4;   // quad (0..3)
  const int cc   = lane & 15;   // col-within-tile = edge slot

  // ---- one-time: linear copy of pre-swizzled 64KB W1 image into LDS ----
  #pragma unroll
  for (int o = 0; o < 8; ++o) {
    int s = (tid + o * 512) * 8;           // shorts; 16B/thread/pass, 8 passes
    *(bf16x8*)(w1t + s) = *(const bf16x8*)(w1i + s);
  }
  if (tid < 128) { b1s[tid] = b1[tid]; g1s[tid] = g1[tid]; e1s[tid] = be1[tid]; }
  else if (tid < 192) { int j = tid - 128; b2s[j] = b2[j]; g2s[j] = g2[j]; e2s[j] = be2[j]; w3s[j] = W3[j]; }
  if (tid == 256) b3s[0] = b3[0];
  __syncthreads();

  // per-lane W2 fragment base (lane-linear global, coalesced, L1-hot)
  const short* w2p = w2L + (lane << 3);

  // ---- cross-tile index prefetch: first tile's gather indices up front ----
  int s0i = 0, d0i = 0, s1i = 0, d1i = 0;
  {
    int r0 = blockIdx.x * 256 + wave * 32 + cc;
    int rc0 = (r0 < E) ? r0 : (E - 1);
    int rc1 = (r0 + 16 < E) ? (r0 + 16) : (E - 1);
    s0i = src[rc0]; d0i = dst[rc0]; s1i = src[rc1]; d1i = dst[rc1];
  }

  // ---- persistent loop over 256-edge tiles; waves free-run (no per-tile sync) ----
  for (int tile = blockIdx.x; tile < ntiles; tile += gridDim.x) {
    const int r0 = tile * 256 + wave * 32 + cc;       // mt=0 edge; mt=1 = r0+16
    const short* pd0 = drugb + (size_t)s0i * 128 + q * 8;
    const short* pq0 = disb  + (size_t)d0i * 128 + q * 8;
    const short* pd1 = drugb + (size_t)s1i * 128 + q * 8;
    const short* pq1 = disb  + (size_t)d1i * 128 + q * 8;

    // prologue: fill the 4-deep ring (kb 0..3, both edge streams) -> 8 loads in flight
    bf16x8 u[4][2];
    #pragma unroll
    for (int i = 0; i < 4; ++i) {
      u[i][0] = *(const bf16x8*)(pd0 + i * 32);
      u[i][1] = *(const bf16x8*)(pd1 + i * 32);
    }

    // prefetch NEXT tile's gather indices (hides idx->gather chain at tile start)
    {
      int tn = tile + gridDim.x;
      if (tn < ntiles) {
        int rn  = tn * 256 + wave * 32 + cc;
        int rcn0 = (rn < E) ? rn : (E - 1);
        int rcn1 = (rn + 16 < E) ? (rn + 16) : (E - 1);
        s0i = src[rcn0]; d0i = dst[rcn0]; s1i = src[rcn1]; d1i = dst[rcn1];
      }
    }

    // ===== layer 1: [256]->[128], K=256, acc init = b1 (bias folded) =====
    f32x4 acc1[8][2];
    #pragma unroll
    for (int nt = 0; nt < 8; ++nt) {
      f32x4 bv = *(const f32x4*)(b1s + nt * 16 + q * 4);
      acc1[nt][0] = bv;
      acc1[nt][1] = bv;
    }

    __builtin_amdgcn_s_setprio(1);
    #pragma unroll
    for (int kb = 0; kb < 8; ++kb) {
      bf16x8 f0 = u[kb & 3][0];
      bf16x8 f1 = u[kb & 3][1];
      if (kb < 4) {                        // refill slot with kb+4 (= pq + kb*32)
        u[kb & 3][0] = *(const bf16x8*)(pq0 + kb * 32);
        u[kb & 3][1] = *(const bf16x8*)(pq1 + kb * 32);
      }
      const char* abase = (const char*)w1t + cc * 512 + ((((kb * 4 + q) ^ (cc & 7))) << 4);
      #pragma unroll
      for (int nt = 0; nt < 8; ++nt) {
        bf16x8 af = *(const bf16x8*)(abase + nt * 8192);   // one read, two MFMAs
        acc1[nt][0] = MFMA16(af, f0, acc1[nt][0]);
        acc1[nt][1] = MFMA16(af, f1, acc1[nt][1]);
      }
    }
    __builtin_amdgcn_s_setprio(0);

    // W2 preload: issue all 16 fragment loads NOW (L1-hot, 64 regs in flight);
    // latency hides under epilogue-1's VALU work.
    bf16x8 wf[16];
    #pragma unroll
    for (int i = 0; i < 16; ++i)
      wf[i] = *(const bf16x8*)(w2p + i * 512);

    // epilogue 1: per-edge-group LN over n=128 (affine-folded), GELU, pack.
    // All arithmetic as f32x4 vector expressions (v_pk_fma_f32 candidates).
    bf16x8 hreg[4][2];
    {
      f32x4 sv0 = acc1[0][0], sv1 = acc1[0][1];
      f32x4 qv0 = acc1[0][0] * acc1[0][0];
      f32x4 qv1 = acc1[0][1] * acc1[0][1];
      #pragma unroll
      for (int nt = 1; nt < 8; ++nt) {
        sv0 += acc1[nt][0];
        sv1 += acc1[nt][1];
        qv0 = acc1[nt][0] * acc1[nt][0] + qv0;
        qv1 = acc1[nt][1] * acc1[nt][1] + qv1;
      }
      float s0 = (sv0[0] + sv0[1]) + (sv0[2] + sv0[3]);
      float s1 = (sv1[0] + sv1[1]) + (sv1[2] + sv1[3]);
      float ss0 = (qv0[0] + qv0[1]) + (qv0[2] + qv0[3]);
      float ss1 = (qv1[0] + qv1[1]) + (qv1[2] + qv1[3]);
      s0  += __shfl_xor(s0, 16);  s0  += __shfl_xor(s0, 32);
      ss0 += __shfl_xor(ss0, 16); ss0 += __shfl_xor(ss0, 32);
      s1  += __shfl_xor(s1, 16);  s1  += __shfl_xor(s1, 32);
      ss1 += __shfl_xor(ss1, 16); ss1 += __shfl_xor(ss1, 32);
      float mu0 = s0 * 0.0078125f, mu1 = s1 * 0.0078125f;
      float va0 = ss0 * 0.0078125f - mu0 * mu0;
      float va1 = ss1 * 0.0078125f - mu1 * mu1;
      va0 = (va0 > 0.f) ? va0 : 0.f;
      va1 = (va1 > 0.f) ? va1 : 0.f;
      float rs0 = __builtin_amdgcn_rsqf(va0 + 1e-5f);
      float rs1 = __builtin_amdgcn_rsqf(va1 + 1e-5f);

      #pragma unroll
      for (int h = 0; h < 4; ++h) {
        f32x4 glo = *(const f32x4*)(g1s + (2 * h) * 16 + q * 4);
        f32x4 elo = *(const f32x4*)(e1s + (2 * h) * 16 + q * 4);
        f32x4 ghi = *(const f32x4*)(g1s + (2 * h + 1) * 16 + q * 4);
        f32x4 ehi = *(const f32x4*)(e1s + (2 * h + 1) * 16 + q * 4);
        // LN affine fold (vector): z = x*(g*rs) + (be - mu*(g*rs))
        f32x4 al0 = glo * rs0, ah0 = ghi * rs0;
        f32x4 al1 = glo * rs1, ah1 = ghi * rs1;
        f32x4 cl0 = elo - al0 * mu0, ch0 = ehi - ah0 * mu0;
        f32x4 cl1 = elo - al1 * mu1, ch1 = ehi - ah1 * mu1;
        f32x4 a0  = gelu4(acc1[2 * h][0]     * al0 + cl0);
        f32x4 b0  = gelu4(acc1[2 * h + 1][0] * ah0 + ch0);
        f32x4 a1  = gelu4(acc1[2 * h][1]     * al1 + cl1);
        f32x4 b1v = gelu4(acc1[2 * h + 1][1] * ah1 + ch1);
        hreg[h][0] = pack8(a0, b0);
        hreg[h][1] = pack8(a1, b1v);
      }
    }

    // ===== layer 2: [128]->[64], register-resident A (wf) and B (hreg) =====
    f32x4 acc2[4][2];
    #pragma unroll
    for (int t = 0; t < 4; ++t) {
      f32x4 bv = *(const f32x4*)(b2s + t * 16 + q * 4);
      acc2[t][0] = bv;
      acc2[t][1] = bv;
    }

    __builtin_amdgcn_s_setprio(1);
    #pragma unroll
    for (int kb2 = 0; kb2 < 4; ++kb2) {
      bf16x8 h0 = hreg[kb2][0];
      bf16x8 h1 = hreg[kb2][1];
      #pragma unroll
      for (int t = 0; t < 4; ++t) {
        bf16x8 af = wf[kb2 * 4 + t];
        acc2[t][0] = MFMA16(af, h0, acc2[t][0]);
        acc2[t][1] = MFMA16(af, h1, acc2[t][1]);
      }
    }
    __builtin_amdgcn_s_setprio(0);

    // epilogue 2: LN over n=64 (affine-folded, vector), GELU, vector dot, store
    {
      f32x4 sv0 = acc2[0][0], sv1 = acc2[0][1];
      f32x4 qv0 = acc2[0][0] * acc2[0][0];
      f32x4 qv1 = acc2[0][1] * acc2[0][1];
      #pragma unroll
      for (int t = 1; t < 4; ++t) {
        sv0 += acc2[t][0];
        sv1 += acc2[t][1];
        qv0 = acc2[t][0] * acc2[t][0] + qv0;
        qv1 = acc2[t][1] * acc2[t][1] + qv1;
      }
      float s0 = (sv0[0] + sv0[1]) + (sv0[2] + sv0[3]);
      float s1 = (sv1[0] + sv1[1]) + (sv1[2] + sv1[3]);
      float ss0 = (qv0[0] + qv0[1]) + (qv0[2] + qv0[3]);
      float ss1 = (qv1[0] + qv1[1]) + (qv1[2] + qv1[3]);
      s0  += __shfl_xor(s0, 16);  s0  += __shfl_xor(s0, 32);
      ss0 += __shfl_xor(ss0, 16); ss0 += __shfl_xor(ss0, 32);
      s1  += __shfl_xor(s1, 16);  s1  += __shfl_xor(s1, 32);
      ss1 += __shfl_xor(ss1, 16); ss1 += __shfl_xor(ss1, 32);
      float mu0 = s0 * 0.015625f, mu1 = s1 * 0.015625f;
      float va0 = ss0 * 0.015625f - mu0 * mu0;
      float va1 = ss1 * 0.015625f - mu1 * mu1;
      va0 = (va0 > 0.f) ? va0 : 0.f;
      va1 = (va1 > 0.f) ? va1 : 0.f;
      float rs0 = __builtin_amdgcn_rsqf(va0 + 1e-5f);
      float rs1 = __builtin_amdgcn_rsqf(va1 + 1e-5f);

      f32x4 d0v = {0.f, 0.f, 0.f, 0.f};
      f32x4 d1v = {0.f, 0.f, 0.f, 0.f};
      #pragma unroll
      for (int t = 0; t < 4; ++t) {
        f32x4 gv = *(const f32x4*)(g2s + t * 16 + q * 4);
        f32x4 ev = *(const f32x4*)(e2s + t * 16 + q * 4);
        f32x4 wv = *(const f32x4*)(w3s + t * 16 + q * 4);
        f32x4 a20 = gv * rs0, a21 = gv * rs1;
        f32x4 c20 = ev - a20 * mu0, c21 = ev - a21 * mu1;
        d0v = gelu4(acc2[t][0] * a20 + c20) * wv + d0v;
        d1v = gelu4(acc2[t][1] * a21 + c21) * wv + d1v;
      }
      float dot0 = (d0v[0] + d0v[1]) + (d0v[2] + d0v[3]);
      float dot1 = (d1v[0] + d1v[1]) + (d1v[2] + d1v[3]);
      dot0 += __shfl_xor(dot0, 16); dot0 += __shfl_xor(dot0, 32);
      dot1 += __shfl_xor(dot1, 16); dot1 += __shfl_xor(dot1, 32);
      if (q == 0) {
        float bias3 = b3s[0];
        if (r0 < E)      out[r0]      = dot0 + bias3;
        if (r0 + 16 < E) out[r0 + 16] = dot1 + bias3;
      }
    }
  }
}

extern "C" void kernel_launch(void* const* d_in, const int* in_sizes, int n_in,
                              void* d_out, int out_size, void* d_ws, size_t ws_size,
                              hipStream_t stream) {
  const float* drug = (const float*)d_in[0];
  const float* dis  = (const float*)d_in[1];
  const int*   src  = (const int*)d_in[2];
  const int*   dst  = (const int*)d_in[3];
  const float* W1   = (const float*)d_in[4];
  const float* b1   = (const float*)d_in[5];
  const float* g1   = (const float*)d_in[6];
  const float* be1  = (const float*)d_in[7];
  const float* W2   = (const float*)d_in[8];
  const float* b2   = (const float*)d_in[9];
  const float* g2   = (const float*)d_in[10];
  const float* be2  = (const float*)d_in[11];
  const float* W3   = (const float*)d_in[12];
  const float* b3   = (const float*)d_in[13];
  float* out = (float*)d_out;

  const int E      = in_sizes[2];
  const int ndrug8 = in_sizes[0] / 8;
  const int ndis8  = in_sizes[1] / 8;
  const int ntiles = (E + 255) / 256;      // 256-edge tiles (8 waves x 32 edges)

  short* w1i   = (short*)d_ws;             // 32768 shorts (full LDS image)
  short* w2L   = w1i + 32768;              // 8192 shorts (W2 lane-linear)
  short* drugb = w2L + 8192;               // bf16 feature tables
  short* disb  = drugb + (size_t)ndrug8 * 8;

  (void)hipFuncSetAttribute((const void*)mlp_fused,
                            hipFuncAttributeMaxDynamicSharedMemorySize, SMEM_BYTES);

  prep_weights<<<dim3(160), dim3(256), 0, stream>>>(W1, W2, w1i, w2L);
  prep_feats<<<dim3((ndrug8 + 255) / 256), dim3(256), 0, stream>>>(drug, drugb, ndrug8);
  prep_feats<<<dim3((ndis8 + 255) / 256), dim3(256), 0, stream>>>(dis, disb, ndis8);

  int grid = 512;
  if (ntiles < grid) grid = ntiles;
  mlp_fused<<<dim3(grid), dim3(512), SMEM_BYTES, stream>>>(
      drugb, disb, src, dst, w1i, w2L,
      b1, g1, be1, b2, g2, be2, W3, b3, out, E, ntiles);
}

// Round 19
// 217.094 us; speedup vs baseline: 1.0852x; 1.0082x over previous
//
#include <hip/hip_runtime.h>
#include <hip/hip_bf16.h>

typedef __attribute__((ext_vector_type(4))) float f32x4;
typedef __attribute__((ext_vector_type(8))) short bf16x8;

#define MFMA16(a, b, c) __builtin_amdgcn_mfma_f32_16x16x32_bf16((a), (b), (c), 0, 0, 0)

// ---- LDS layout (bytes): W1 64K + params ~2.6K = 68128 (R7+-proven).
#define W1T_OFF 0        // 128 n-rows x 256 k bf16, XOR-swizzled 8-chunks
#define B1_OFF  65536
#define G1_OFF  66048
#define E1_OFF  66560
#define B2_OFF  67072
#define G2_OFF  67328
#define E2_OFF  67584
#define W3_OFF  67840
#define B3_OFF  68096
#define SMEM_BYTES 68128

__device__ __forceinline__ short f2bf(float x) {
  __hip_bfloat16 h = __float2bfloat16(x);
  return __builtin_bit_cast(short, h);
}

__device__ __forceinline__ bf16x8 pack8(f32x4 a, f32x4 b) {
  bf16x8 r;
  r[0] = f2bf(a[0]); r[1] = f2bf(a[1]); r[2] = f2bf(a[2]); r[3] = f2bf(a[3]);
  r[4] = f2bf(b[0]); r[5] = f2bf(b[1]); r[6] = f2bf(b[2]); r[7] = f2bf(b[3]);
  return r;
}

// GELU via logistic CDF fit, log2e folded: z / (1 + exp2(z*(c1 + c2 z^2))).
// |err| <~ 5e-4. PROVEN: R4-R18 passed at absmax 0.0078. (R15's trans-free
// quartic FAILED accuracy 0.0332 -- do not retry without a rigorous bound.)
// Vector form: poly pre/post as f32x4 (v_pk_fma_f32 dual-issue candidates);
// exp2/rcp have no packed form, stay scalar.
__device__ __forceinline__ f32x4 gelu4(f32x4 z) {
  f32x4 s = z * z;
  f32x4 y = z * (s * -0.10180479f + -2.3048496f);
  f32x4 t;
  t[0] = __builtin_amdgcn_exp2f(y[0]);
  t[1] = __builtin_amdgcn_exp2f(y[1]);
  t[2] = __builtin_amdgcn_exp2f(y[2]);
  t[3] = __builtin_amdgcn_exp2f(y[3]);
  f32x4 d = t + 1.0f;
  f32x4 r;
  r[0] = __builtin_amdgcn_rcpf(d[0]);
  r[1] = __builtin_amdgcn_rcpf(d[1]);
  r[2] = __builtin_amdgcn_rcpf(d[2]);
  r[3] = __builtin_amdgcn_rcpf(d[3]);
  return z * r;
}

// One-time weight prep into workspace (verified R9-R18):
//   w1i: W1 XOR-swizzled bf16 LDS image.
//   w2L: W2 pi-permuted fragments, lane-linear [(kb2*4+t)*512 + lane*8 + e].
//   forward pi: n -> k = (n>>5)*32 + ((n>>2)&3)*8 + ((n>>4)&1)*4 + (n&3)
__global__ __launch_bounds__(256) void prep_weights(
    const float* __restrict__ W1, const float* __restrict__ W2,
    short* __restrict__ w1i, short* __restrict__ w2L) {
  int idx = blockIdx.x * 256 + threadIdx.x;
  if (idx < 32768) {                       // W1 [k=256][n=128] row-major
    int k = idx >> 7, n = idx & 127;
    w1i[n * 256 + ((((k >> 3) ^ (n & 7)) << 3) | (k & 7))] = f2bf(W1[idx]);
  } else if (idx < 40960) {                // W2 [n=128][n2=64] row-major
    int j = idx - 32768;
    int n = j >> 6, n2 = j & 63;
    int kb2 = n >> 5;
    int qf = (n >> 2) & 3;
    int e = ((n >> 4) & 1) * 4 + (n & 3);
    int t = n2 >> 4, cc2 = n2 & 15;
    w2L[(kb2 * 4 + t) * 512 + (qf * 16 + cc2) * 8 + e] = f2bf(W2[j]);
  }
}

// One-time feature-table conversion f32 -> bf16 (R8-proven).
__global__ __launch_bounds__(256) void prep_feats(
    const float* __restrict__ f, short* __restrict__ o, int n8) {
  int idx = blockIdx.x * 256 + threadIdx.x;
  if (idx < n8) {
    f32x4 a = *(const f32x4*)(f + idx * 8);
    f32x4 b = *(const f32x4*)(f + idx * 8 + 4);
    *(bf16x8*)(o + idx * 8) = pack8(a, b);
  }
}

// Fused gather + (256->128 LN GELU) + (128->64 LN GELU) + (64->1).
// 8 waves/block (512 thr), mt=2 (32 edges/wave), 256-edge tiles, (512,1).
// R19 vs R18 (218.9us headline / ~158 steady): CROSS-TILE RING ROTATION.
// R18's counters (VALU 51->40% but dur flat) proved the kernel is now
// dependency-latency-bound, not issue-bound. Largest naked latency: the
// tile-start ring fill (8 gather loads consumed ~10 insts later). Fix is
// register-FREE by lifetime coincidence: wf[16] (64 regs) dies exactly at
// layer-2's end, and the ring u[4][2] (64 regs) is dead from layer-1's end
// to the next tile -> issue tile t+1's ring fill right after layer-2 of
// tile t (indices already prefetched). Loads get epilogue-2 (~1000cy) to
// land. Sequencing: current pq ptrs computed BEFORE index prefetch
// overwrites d0i/d1i; pd ptrs not needed inside the tile anymore.
// pi-trick: layer-2 B operand = layer-1 accumulators (no H1 round-trip).
__global__ __launch_bounds__(512, 1) void mlp_fused(
    const short* __restrict__ drugb, const short* __restrict__ disb,
    const int* __restrict__ src, const int* __restrict__ dst,
    const short* __restrict__ w1i, const short* __restrict__ w2L,
    const float* __restrict__ b1, const float* __restrict__ g1, const float* __restrict__ be1,
    const float* __restrict__ b2, const float* __restrict__ g2, const float* __restrict__ be2,
    const float* __restrict__ W3, const float* __restrict__ b3,
    float* __restrict__ out, int E, int ntiles) {
  extern __shared__ char smem[];
  short* w1t = (short*)(smem + W1T_OFF);
  float* b1s = (float*)(smem + B1_OFF);
  float* g1s = (float*)(smem + G1_OFF);
  float* e1s = (float*)(smem + E1_OFF);
  float* b2s = (float*)(smem + B2_OFF);
  float* g2s = (float*)(smem + G2_OFF);
  float* e2s = (float*)(smem + E2_OFF);
  float* w3s = (float*)(smem + W3_OFF);
  float* b3s = (float*)(smem + B3_OFF);

  const int tid  = threadIdx.x;
  const int wave = tid >> 6;    // 0..7
  const int lane = tid & 63;
  const int q    = lane >> 4;   // quad (0..3)
  const int cc   = lane & 15;   // col-within-tile = edge slot

  // ---- one-time: linear copy of pre-swizzled 64KB W1 image into LDS ----
  #pragma unroll
  for (int o = 0; o < 8; ++o) {
    int s = (tid + o * 512) * 8;           // shorts; 16B/thread/pass, 8 passes
    *(bf16x8*)(w1t + s) = *(const bf16x8*)(w1i + s);
  }
  if (tid < 128) { b1s[tid] = b1[tid]; g1s[tid] = g1[tid]; e1s[tid] = be1[tid]; }
  else if (tid < 192) { int j = tid - 128; b2s[j] = b2[j]; g2s[j] = g2[j]; e2s[j] = be2[j]; w3s[j] = W3[j]; }
  if (tid == 256) b3s[0] = b3[0];
  __syncthreads();

  // per-lane W2 fragment base (lane-linear global, coalesced, L1-hot)
  const short* w2p = w2L + (lane << 3);

  // ---- first tile's indices + ring fill (prologue) ----
  int s0i = 0, d0i = 0, s1i = 0, d1i = 0;
  {
    int r0 = blockIdx.x * 256 + wave * 32 + cc;
    int rc0 = (r0 < E) ? r0 : (E - 1);
    int rc1 = (r0 + 16 < E) ? (r0 + 16) : (E - 1);
    s0i = src[rc0]; d0i = dst[rc0]; s1i = src[rc1]; d1i = dst[rc1];
  }
  bf16x8 u[4][2];
  {
    const short* pd0 = drugb + (size_t)s0i * 128 + q * 8;
    const short* pd1 = drugb + (size_t)s1i * 128 + q * 8;
    #pragma unroll
    for (int i = 0; i < 4; ++i) {
      u[i][0] = *(const bf16x8*)(pd0 + i * 32);
      u[i][1] = *(const bf16x8*)(pd1 + i * 32);
    }
  }

  // ---- persistent loop over 256-edge tiles; waves free-run (no per-tile sync) ----
  for (int tile = blockIdx.x; tile < ntiles; tile += gridDim.x) {
    const int r0 = tile * 256 + wave * 32 + cc;       // mt=0 edge; mt=1 = r0+16
    // current-tile pq pointers BEFORE the index prefetch overwrites d0i/d1i
    const short* pq0 = disb + (size_t)d0i * 128 + q * 8;
    const short* pq1 = disb + (size_t)d1i * 128 + q * 8;

    // prefetch NEXT tile's gather indices (feeds the post-layer-2 ring fill)
    {
      int tn = tile + gridDim.x;
      if (tn < ntiles) {
        int rn  = tn * 256 + wave * 32 + cc;
        int rcn0 = (rn < E) ? rn : (E - 1);
        int rcn1 = (rn + 16 < E) ? (rn + 16) : (E - 1);
        s0i = src[rcn0]; d0i = dst[rcn0]; s1i = src[rcn1]; d1i = dst[rcn1];
      }
    }

    // ===== layer 1: [256]->[128], K=256, acc init = b1 (bias folded);
    // ring u pre-filled (prologue or previous tile's rotation) =====
    f32x4 acc1[8][2];
    #pragma unroll
    for (int nt = 0; nt < 8; ++nt) {
      f32x4 bv = *(const f32x4*)(b1s + nt * 16 + q * 4);
      acc1[nt][0] = bv;
      acc1[nt][1] = bv;
    }

    __builtin_amdgcn_s_setprio(1);
    #pragma unroll
    for (int kb = 0; kb < 8; ++kb) {
      bf16x8 f0 = u[kb & 3][0];
      bf16x8 f1 = u[kb & 3][1];
      if (kb < 4) {                        // refill slot with kb+4 (= pq + kb*32)
        u[kb & 3][0] = *(const bf16x8*)(pq0 + kb * 32);
        u[kb & 3][1] = *(const bf16x8*)(pq1 + kb * 32);
      }
      const char* abase = (const char*)w1t + cc * 512 + ((((kb * 4 + q) ^ (cc & 7))) << 4);
      #pragma unroll
      for (int nt = 0; nt < 8; ++nt) {
        bf16x8 af = *(const bf16x8*)(abase + nt * 8192);   // one read, two MFMAs
        acc1[nt][0] = MFMA16(af, f0, acc1[nt][0]);
        acc1[nt][1] = MFMA16(af, f1, acc1[nt][1]);
      }
    }
    __builtin_amdgcn_s_setprio(0);

    // W2 preload: 16 fragment loads (L1-hot); latency hides under epilogue-1.
    bf16x8 wf[16];
    #pragma unroll
    for (int i = 0; i < 16; ++i)
      wf[i] = *(const bf16x8*)(w2p + i * 512);

    // epilogue 1: per-edge-group LN over n=128 (affine-folded, vector), GELU, pack.
    bf16x8 hreg[4][2];
    {
      f32x4 sv0 = acc1[0][0], sv1 = acc1[0][1];
      f32x4 qv0 = acc1[0][0] * acc1[0][0];
      f32x4 qv1 = acc1[0][1] * acc1[0][1];
      #pragma unroll
      for (int nt = 1; nt < 8; ++nt) {
        sv0 += acc1[nt][0];
        sv1 += acc1[nt][1];
        qv0 = acc1[nt][0] * acc1[nt][0] + qv0;
        qv1 = acc1[nt][1] * acc1[nt][1] + qv1;
      }
      float s0 = (sv0[0] + sv0[1]) + (sv0[2] + sv0[3]);
      float s1 = (sv1[0] + sv1[1]) + (sv1[2] + sv1[3]);
      float ss0 = (qv0[0] + qv0[1]) + (qv0[2] + qv0[3]);
      float ss1 = (qv1[0] + qv1[1]) + (qv1[2] + qv1[3]);
      s0  += __shfl_xor(s0, 16);  s0  += __shfl_xor(s0, 32);
      ss0 += __shfl_xor(ss0, 16); ss0 += __shfl_xor(ss0, 32);
      s1  += __shfl_xor(s1, 16);  s1  += __shfl_xor(s1, 32);
      ss1 += __shfl_xor(ss1, 16); ss1 += __shfl_xor(ss1, 32);
      float mu0 = s0 * 0.0078125f, mu1 = s1 * 0.0078125f;
      float va0 = ss0 * 0.0078125f - mu0 * mu0;
      float va1 = ss1 * 0.0078125f - mu1 * mu1;
      va0 = (va0 > 0.f) ? va0 : 0.f;
      va1 = (va1 > 0.f) ? va1 : 0.f;
      float rs0 = __builtin_amdgcn_rsqf(va0 + 1e-5f);
      float rs1 = __builtin_amdgcn_rsqf(va1 + 1e-5f);

      #pragma unroll
      for (int h = 0; h < 4; ++h) {
        f32x4 glo = *(const f32x4*)(g1s + (2 * h) * 16 + q * 4);
        f32x4 elo = *(const f32x4*)(e1s + (2 * h) * 16 + q * 4);
        f32x4 ghi = *(const f32x4*)(g1s + (2 * h + 1) * 16 + q * 4);
        f32x4 ehi = *(const f32x4*)(e1s + (2 * h + 1) * 16 + q * 4);
        f32x4 al0 = glo * rs0, ah0 = ghi * rs0;
        f32x4 al1 = glo * rs1, ah1 = ghi * rs1;
        f32x4 cl0 = elo - al0 * mu0, ch0 = ehi - ah0 * mu0;
        f32x4 cl1 = elo - al1 * mu1, ch1 = ehi - ah1 * mu1;
        f32x4 a0  = gelu4(acc1[2 * h][0]     * al0 + cl0);
        f32x4 b0  = gelu4(acc1[2 * h + 1][0] * ah0 + ch0);
        f32x4 a1  = gelu4(acc1[2 * h][1]     * al1 + cl1);
        f32x4 b1v = gelu4(acc1[2 * h + 1][1] * ah1 + ch1);
        hreg[h][0] = pack8(a0, b0);
        hreg[h][1] = pack8(a1, b1v);
      }
    }

    // ===== layer 2: [128]->[64], register-resident A (wf) and B (hreg) =====
    f32x4 acc2[4][2];
    #pragma unroll
    for (int t = 0; t < 4; ++t) {
      f32x4 bv = *(const f32x4*)(b2s + t * 16 + q * 4);
      acc2[t][0] = bv;
      acc2[t][1] = bv;
    }

    __builtin_amdgcn_s_setprio(1);
    #pragma unroll
    for (int kb2 = 0; kb2 < 4; ++kb2) {
      bf16x8 h0 = hreg[kb2][0];
      bf16x8 h1 = hreg[kb2][1];
      #pragma unroll
      for (int t = 0; t < 4; ++t) {
        bf16x8 af = wf[kb2 * 4 + t];
        acc2[t][0] = MFMA16(af, h0, acc2[t][0]);
        acc2[t][1] = MFMA16(af, h1, acc2[t][1]);
      }
    }
    __builtin_amdgcn_s_setprio(0);

    // ---- ring rotation: issue NEXT tile's pd gather now (wf just died ->
    // register-free). Loads land during epilogue-2 (~1000cy of cover). ----
    {
      const short* pdn0 = drugb + (size_t)s0i * 128 + q * 8;
      const short* pdn1 = drugb + (size_t)s1i * 128 + q * 8;
      #pragma unroll
      for (int i = 0; i < 4; ++i) {
        u[i][0] = *(const bf16x8*)(pdn0 + i * 32);
        u[i][1] = *(const bf16x8*)(pdn1 + i * 32);
      }
    }

    // epilogue 2: LN over n=64 (affine-folded, vector), GELU, vector dot, store
    {
      f32x4 sv0 = acc2[0][0], sv1 = acc2[0][1];
      f32x4 qv0 = acc2[0][0] * acc2[0][0];
      f32x4 qv1 = acc2[0][1] * acc2[0][1];
      #pragma unroll
      for (int t = 1; t < 4; ++t) {
        sv0 += acc2[t][0];
        sv1 += acc2[t][1];
        qv0 = acc2[t][0] * acc2[t][0] + qv0;
        qv1 = acc2[t][1] * acc2[t][1] + qv1;
      }
      float s0 = (sv0[0] + sv0[1]) + (sv0[2] + sv0[3]);
      float s1 = (sv1[0] + sv1[1]) + (sv1[2] + sv1[3]);
      float ss0 = (qv0[0] + qv0[1]) + (qv0[2] + qv0[3]);
      float ss1 = (qv1[0] + qv1[1]) + (qv1[2] + qv1[3]);
      s0  += __shfl_xor(s0, 16);  s0  += __shfl_xor(s0, 32);
      ss0 += __shfl_xor(ss0, 16); ss0 += __shfl_xor(ss0, 32);
      s1  += __shfl_xor(s1, 16);  s1  += __shfl_xor(s1, 32);
      ss1 += __shfl_xor(ss1, 16); ss1 += __shfl_xor(ss1, 32);
      float mu0 = s0 * 0.015625f, mu1 = s1 * 0.015625f;
      float va0 = ss0 * 0.015625f - mu0 * mu0;
      float va1 = ss1 * 0.015625f - mu1 * mu1;
      va0 = (va0 > 0.f) ? va0 : 0.f;
      va1 = (va1 > 0.f) ? va1 : 0.f;
      float rs0 = __builtin_amdgcn_rsqf(va0 + 1e-5f);
      float rs1 = __builtin_amdgcn_rsqf(va1 + 1e-5f);

      f32x4 d0v = {0.f, 0.f, 0.f, 0.f};
      f32x4 d1v = {0.f, 0.f, 0.f, 0.f};
      #pragma unroll
      for (int t = 0; t < 4; ++t) {
        f32x4 gv = *(const f32x4*)(g2s + t * 16 + q * 4);
        f32x4 ev = *(const f32x4*)(e2s + t * 16 + q * 4);
        f32x4 wv = *(const f32x4*)(w3s + t * 16 + q * 4);
        f32x4 a20 = gv * rs0, a21 = gv * rs1;
        f32x4 c20 = ev - a20 * mu0, c21 = ev - a21 * mu1;
        d0v = gelu4(acc2[t][0] * a20 + c20) * wv + d0v;
        d1v = gelu4(acc2[t][1] * a21 + c21) * wv + d1v;
      }
      float dot0 = (d0v[0] + d0v[1]) + (d0v[2] + d0v[3]);
      float dot1 = (d1v[0] + d1v[1]) + (d1v[2] + d1v[3]);
      dot0 += __shfl_xor(dot0, 16); dot0 += __shfl_xor(dot0, 32);
      dot1 += __shfl_xor(dot1, 16); dot1 += __shfl_xor(dot1, 32);
      if (q == 0) {
        float bias3 = b3s[0];
        if (r0 < E)      out[r0]      = dot0 + bias3;
        if (r0 + 16 < E) out[r0 + 16] = dot1 + bias3;
      }
    }
  }
}

extern "C" void kernel_launch(void* const* d_in, const int* in_sizes, int n_in,
                              void* d_out, int out_size, void* d_ws, size_t ws_size,
                              hipStream_t stream) {
  const float* drug = (const float*)d_in[0];
  const float* dis  = (const float*)d_in[1];
  const int*   src  = (const int*)d_in[2];
  const int*   dst  = (const int*)d_in[3];
  const float* W1   = (const float*)d_in[4];
  const float* b1   = (const float*)d_in[5];
  const float* g1   = (const float*)d_in[6];
  const float* be1  = (const float*)d_in[7];
  const float* W2   = (const float*)d_in[8];
  const float* b2   = (const float*)d_in[9];
  const float* g2   = (const float*)d_in[10];
  const float* be2  = (const float*)d_in[11];
  const float* W3   = (const float*)d_in[12];
  const float* b3   = (const float*)d_in[13];
  float* out = (float*)d_out;

  const int E      = in_sizes[2];
  const int ndrug8 = in_sizes[0] / 8;
  const int ndis8  = in_sizes[1] / 8;
  const int ntiles = (E + 255) / 256;      // 256-edge tiles (8 waves x 32 edges)

  short* w1i   = (short*)d_ws;             // 32768 shorts (full LDS image)
  short* w2L   = w1i + 32768;              // 8192 shorts (W2 lane-linear)
  short* drugb = w2L + 8192;               // bf16 feature tables
  short* disb  = drugb + (size_t)ndrug8 * 8;

  (void)hipFuncSetAttribute((const void*)mlp_fused,
                            hipFuncAttributeMaxDynamicSharedMemorySize, SMEM_BYTES);

  prep_weights<<<dim3(160), dim3(256), 0, stream>>>(W1, W2, w1i, w2L);
  prep_feats<<<dim3((ndrug8 + 255) / 256), dim3(256), 0, stream>>>(drug, drugb, ndrug8);
  prep_feats<<<dim3((ndis8 + 255) / 256), dim3(256), 0, stream>>>(dis, disb, ndis8);

  int grid = 512;
  if (ntiles < grid) grid = ntiles;
  mlp_fused<<<dim3(grid), dim3(512), SMEM_BYTES, stream>>>(
      drugb, disb, src, dst, w1i, w2L,
      b1, g1, be1, b2, g2, be2, W3, b3, out, E, ntiles);
}